// Round 15
// baseline (5016.799 us; speedup 1.0000x reference)
//
#include <hip/hip_runtime.h>

#define Bb 256
#define Ll 1024
#define Ff 64
#define Ee 128
#define Hh 128
#define CH 32

typedef _Float16 h2v __attribute__((ext_vector_type(2)));

__device__ __forceinline__ unsigned pack_h2(float a, float b) {
  h2v v; v[0] = (_Float16)a; v[1] = (_Float16)b;
  return __builtin_bit_cast(unsigned, v);
}
__device__ __forceinline__ float dot2(unsigned w, unsigned x, float acc) {
#if defined(__has_builtin) && __has_builtin(__builtin_amdgcn_fdot2)
  return __builtin_amdgcn_fdot2(__builtin_bit_cast(h2v, w),
                                __builtin_bit_cast(h2v, x), acc, false);
#else
  h2v wv = __builtin_bit_cast(h2v, w), xv = __builtin_bit_cast(h2v, x);
  acc = fmaf((float)wv[0], (float)xv[0], acc);
  return fmaf((float)wv[1], (float)xv[1], acc);
#endif
}
__device__ __forceinline__ float dppadd1(float v) {   // + lane^1
  int s = __builtin_amdgcn_mov_dpp(__builtin_bit_cast(int, v), 0xB1, 0xF, 0xF, true);
  return v + __builtin_bit_cast(float, s);
}
__device__ __forceinline__ float dppadd2(float v) {   // + lane^2
  int s = __builtin_amdgcn_mov_dpp(__builtin_bit_cast(int, v), 0x4E, 0xF, 0xF, true);
  return v + __builtin_bit_cast(float, s);
}
__device__ __forceinline__ float qsum(float a0, float a1) {
  return dppadd2(dppadd1(a0 + a1));   // sum across the 4-lane quad (pure VALU)
}
__device__ __forceinline__ float fast_tanh(float x) {
  float e = __expf(2.0f * x);
  return 1.0f - 2.0f / (e + 1.0f);
}
__device__ __forceinline__ float fast_sigmoid(float x) {
  return 1.0f / (1.0f + __expf(-x));
}

// 32-wide K-slice matvec: 16 dot2, 2 chains, quad reduce (result quad-uniform)
__device__ __forceinline__ float mv16(const unsigned* __restrict__ w,
                                      const unsigned* __restrict__ v, int q0) {
  float a0 = 0.0f, a1 = 0.0f;
#pragma unroll
  for (int c = 0; c < 4; ++c) {
    const uint4 hv = *(const uint4*)&v[q0 + 4 * c];
    a0 = dot2(w[4*c+0], hv.x, a0); a1 = dot2(w[4*c+1], hv.y, a1);
    a0 = dot2(w[4*c+2], hv.z, a0); a1 = dot2(w[4*c+3], hv.w, a1);
  }
  return qsum(a0, a1);
}
// gi gate from LDS-resident (XOR-swizzled) Wih row
__device__ __forceinline__ float giq(const unsigned* __restrict__ wrow,
                                     const unsigned* __restrict__ xe,
                                     int q0, int swi) {
  float g0 = 0.0f, g1 = 0.0f;
#pragma unroll
  for (int c = 0; c < 4; ++c) {
    const uint4 xv = *(const uint4*)&xe[q0 + 4 * c];
    const uint4 w4 = *(const uint4*)&wrow[(q0 + 4 * c) ^ swi];
    g0 = dot2(w4.x, xv.x, g0); g1 = dot2(w4.y, xv.y, g1);
    g0 = dot2(w4.z, xv.z, g0); g1 = dot2(w4.w, xv.w, g1);
  }
  return qsum(g0, g1);
}

// 1024 threads: waves 0-7 = h-engine (r12 structure, 4-way K-split);
// waves 8-15 = x-engine (xe + gi + LayerNorm of step t-1).
__global__ __launch_bounds__(1024, 1) void k_fused(
    const float* __restrict__ x, const float* __restrict__ dtp,
    const int* __restrict__ mask,
    const float* __restrict__ Wx, const float* __restrict__ bx,
    const float* __restrict__ W1, const float* __restrict__ b1,
    const float* __restrict__ W2, const float* __restrict__ b2,
    const float* __restrict__ Wih, const float* __restrict__ bih,
    const float* __restrict__ Whh, const float* __restrict__ bhh,
    const float* __restrict__ lng, const float* __restrict__ lnb,
    const float* __restrict__ Whd, const float* __restrict__ bhp,
    float* __restrict__ out)
{
  const int b = blockIdx.x;
  const int tid = threadIdx.x;
  const int lane = tid & 63;
  const int wv = tid >> 6;            // 0..15
  const bool isH = (wv < 8);
  const int wr = wv & 7;              // engine-local wave id
  const int jl = lane >> 2;           // 0..15
  const int ks = lane & 3;            // 0..3
  const int j = (wr << 4) + jl;       // 0..127 (output row, both engines)
  const int q0 = ks << 4;             // u32 base in 64-u32 (K=128) arrays
  const int q0x = ks << 3;            // u32 base in 32-u32 (F=64) rows
  const int swi = (j & 15) << 2;

  __shared__ int act_lds[Ll];                               // 4 KB
  __shared__ __align__(16) unsigned wih_lds[3 * Hh * 64];   // 96 KB, swizzled
  __shared__ __align__(16) unsigned x16[CH * 32];           // 4 KB
  __shared__ __align__(16) unsigned xe16[Ee / 2];
  __shared__ __align__(16) unsigned u16[Hh / 2];
  __shared__ __align__(16) unsigned h16[2][Hh / 2];
  __shared__ float gi_f[3 * Hh];                            // 1.5 KB f32
  __shared__ float hLN[2][Hh];                              // 1 KB f32
  __shared__ float bias_lds[3 * Hh];                        // bhh only
  __shared__ float dt_ch[CH];
  __shared__ int   m_ch[CH];
  __shared__ float lnpart[2][3];
  __shared__ float cc_lds[2];

  // ---- act prepass (coalesced) ----
  for (int t0 = tid; t0 < Ll; t0 += 1024) {
    int a = 0;
#pragma unroll 8
    for (int bb = 0; bb < Bb; ++bb) a |= mask[(size_t)bb * Ll + t0];
    act_lds[t0] = a;
  }
  // ---- Wih -> LDS f16 pairs, XOR-swizzled per 64-word row ----
  for (int idx = tid; idx < 3 * Hh * 64; idx += 1024) {
    const int r = idx >> 6, w = idx & 63;
    wih_lds[(r << 6) | (w ^ ((r & 15) << 2))] =
        pack_h2(Wih[(size_t)r * Ee + 2 * w], Wih[(size_t)r * Ee + 2 * w + 1]);
  }
  for (int i = tid; i < 3 * Hh; i += 1024) bias_lds[i] = bhh[i];
  if (tid == 0) {
    float s1 = 0.0f, s0 = 0.0f;
    for (int i = 0; i < Hh; ++i) { s1 += lng[i] * Whd[i]; s0 += lnb[i] * Whd[i]; }
    cc_lds[0] = s1; cc_lds[1] = s0 + bhp[0];
  }

  // ---- engine-specific stationary registers ----
  unsigned w1h[16], w2h[16], whr[16], whz[16], whn[16];   // h-engine (80 u32)
  unsigned wxh[8];                                        // x-engine
  float b1j = 0.0f, b2j = 0.0f, bxj = 0.0f;
  float birj = 0.0f, bizj = 0.0f, binj = 0.0f;
  if (isH) {
#pragma unroll
    for (int ii = 0; ii < 4; ++ii) {
      float4 a4;
      a4 = *(const float4*)&W1[(size_t)j * Hh + (ks << 5) + 4 * ii];
      w1h[2*ii] = pack_h2(a4.x, a4.y); w1h[2*ii+1] = pack_h2(a4.z, a4.w);
      a4 = *(const float4*)&W1[(size_t)j * Hh + (ks << 5) + 16 + 4 * ii];
      w1h[8+2*ii] = pack_h2(a4.x, a4.y); w1h[8+2*ii+1] = pack_h2(a4.z, a4.w);
      a4 = *(const float4*)&W2[(size_t)j * Hh + (ks << 5) + 4 * ii];
      w2h[2*ii] = pack_h2(a4.x, a4.y); w2h[2*ii+1] = pack_h2(a4.z, a4.w);
      a4 = *(const float4*)&W2[(size_t)j * Hh + (ks << 5) + 16 + 4 * ii];
      w2h[8+2*ii] = pack_h2(a4.x, a4.y); w2h[8+2*ii+1] = pack_h2(a4.z, a4.w);
      a4 = *(const float4*)&Whh[(size_t)j * Hh + (ks << 5) + 4 * ii];
      whr[2*ii] = pack_h2(a4.x, a4.y); whr[2*ii+1] = pack_h2(a4.z, a4.w);
      a4 = *(const float4*)&Whh[(size_t)j * Hh + (ks << 5) + 16 + 4 * ii];
      whr[8+2*ii] = pack_h2(a4.x, a4.y); whr[8+2*ii+1] = pack_h2(a4.z, a4.w);
      a4 = *(const float4*)&Whh[(size_t)(Hh + j) * Hh + (ks << 5) + 4 * ii];
      whz[2*ii] = pack_h2(a4.x, a4.y); whz[2*ii+1] = pack_h2(a4.z, a4.w);
      a4 = *(const float4*)&Whh[(size_t)(Hh + j) * Hh + (ks << 5) + 16 + 4 * ii];
      whz[8+2*ii] = pack_h2(a4.x, a4.y); whz[8+2*ii+1] = pack_h2(a4.z, a4.w);
      a4 = *(const float4*)&Whh[(size_t)(2 * Hh + j) * Hh + (ks << 5) + 4 * ii];
      whn[2*ii] = pack_h2(a4.x, a4.y); whn[2*ii+1] = pack_h2(a4.z, a4.w);
      a4 = *(const float4*)&Whh[(size_t)(2 * Hh + j) * Hh + (ks << 5) + 16 + 4 * ii];
      whn[8+2*ii] = pack_h2(a4.x, a4.y); whn[8+2*ii+1] = pack_h2(a4.z, a4.w);
    }
    b1j = b1[j]; b2j = b2[j];
  } else {
#pragma unroll
    for (int ii = 0; ii < 4; ++ii) {
      const float4 a4 = *(const float4*)&Wx[(size_t)j * Ff + (ks << 4) + 4 * ii];
      wxh[2*ii] = pack_h2(a4.x, a4.y); wxh[2*ii+1] = pack_h2(a4.z, a4.w);
    }
    bxj = bx[j];
    birj = bih[j]; bizj = bih[Hh + j]; binj = bih[2 * Hh + j];
  }
  // LN lane data for waves 8,9
  const int lidx = ((wv - 8) << 6) + lane;   // 0..127 for wv 8,9
  float gw_l = 0.0f;
  if (wv == 8 || wv == 9) gw_l = lng[lidx] * Whd[lidx];

  if (tid < Hh) ((unsigned*)h16)[tid] = 0u;
  float hreg = 0.0f;
  float acc = 0.0f, cnt = 0.0f;       // live on tid 512 only
  int mprev = 0;
  int pp = 0;
  __syncthreads();

#pragma unroll 1
  for (int t = 0; t < Ll; ++t) {
    const int tc = t & (CH - 1);
    if (tc == 0) {
      const int st = tid >> 5, g = tid & 31;
      const float2 a = *(const float2*)(x + ((size_t)b * Ll + t + st) * Ff + g * 2);
      x16[st * 32 + g] = pack_h2(a.x, a.y);
      if (tid < CH) dt_ch[tid] = dtp[(size_t)b * Ll + t + tid];
      else if (tid < 2 * CH) m_ch[tid - CH] = mask[(size_t)b * Ll + t + (tid - CH)];
      __syncthreads();
    }
    const float dtv = dt_ch[tc];
    const int m = m_ch[tc];
    const float stepv = dtv * (float)m * 0.25f;
    unsigned* hcur = h16[pp];

    // ---- phase A: h: substep0 mv1 | x: xe ----
    if (isH) {
      const float uu = fast_tanh(mv16(w1h, hcur, q0) + b1j);
      if (ks == 0) ((_Float16*)u16)[j] = (_Float16)uu;
    } else {
      const unsigned* xr = &x16[tc * 32];
      float p0 = 0.0f, p1 = 0.0f;
#pragma unroll
      for (int c = 0; c < 2; ++c) {
        const uint4 xv = *(const uint4*)&xr[q0x + 4 * c];
        p0 = dot2(wxh[4*c+0], xv.x, p0); p1 = dot2(wxh[4*c+1], xv.y, p1);
        p0 = dot2(wxh[4*c+2], xv.z, p0); p1 = dot2(wxh[4*c+3], xv.w, p1);
      }
      const float xev = fmaxf(qsum(p0, p1) + bxj, 0.0f);
      if (ks == 0) ((_Float16*)xe16)[j] = (_Float16)xev;
    }
    __syncthreads();                         // B1

    // ---- phase B: h: substep0 mv2 | x: gi_r ----
    if (isH) {
      hreg = fmaf(stepv, mv16(w2h, u16, q0) + b2j, hreg);
      if (ks == 0) ((_Float16*)hcur)[j] = (_Float16)hreg;
    } else {
      const float g = giq(&wih_lds[j << 6], xe16, q0, swi) + birj;
      if (ks == 0) gi_f[j] = g;
    }
    __syncthreads();                         // B2

    // ---- phase C: h: substep1 mv1 | x: gi_z ----
    if (isH) {
      const float uu = fast_tanh(mv16(w1h, hcur, q0) + b1j);
      if (ks == 0) ((_Float16*)u16)[j] = (_Float16)uu;
    } else {
      const float g = giq(&wih_lds[(Hh + j) << 6], xe16, q0, swi) + bizj;
      if (ks == 0) gi_f[Hh + j] = g;
    }
    __syncthreads();                         // B3

    // ---- phase D: h: substep1 mv2 | x: gi_n ----
    if (isH) {
      hreg = fmaf(stepv, mv16(w2h, u16, q0) + b2j, hreg);
      if (ks == 0) ((_Float16*)hcur)[j] = (_Float16)hreg;
    } else {
      const float g = giq(&wih_lds[(2 * Hh + j) << 6], xe16, q0, swi) + binj;
      if (ks == 0) gi_f[2 * Hh + j] = g;
    }
    __syncthreads();                         // B4

    // ---- phase E: h: substep2 mv1 | x(waves 8,9): LN partials of t-1 ----
    if (isH) {
      const float uu = fast_tanh(mv16(w1h, hcur, q0) + b1j);
      if (ks == 0) ((_Float16*)u16)[j] = (_Float16)uu;
    } else if (wv < 10 && t > 0) {
      const float hv = hLN[(t & 1) ^ 1][lidx];
      float s1 = hv, s2 = hv * hv, sd = hv * gw_l;
#pragma unroll
      for (int o = 1; o < 64; o <<= 1) {
        s1 += __shfl_xor(s1, o); s2 += __shfl_xor(s2, o); sd += __shfl_xor(sd, o);
      }
      if (lane == 0) {
        lnpart[wv - 8][0] = s1; lnpart[wv - 8][1] = s2; lnpart[wv - 8][2] = sd;
      }
    }
    __syncthreads();                         // B5

    // ---- phase F: h: substep2 mv2 | tid512: LN finalize of t-1 ----
    if (isH) {
      hreg = fmaf(stepv, mv16(w2h, u16, q0) + b2j, hreg);
      if (ks == 0) ((_Float16*)hcur)[j] = (_Float16)hreg;
    } else if (tid == 512) {
      if (t > 0 && mprev) {
        const float S1 = lnpart[0][0] + lnpart[1][0];
        const float S2 = lnpart[0][1] + lnpart[1][1];
        const float SD = lnpart[0][2] + lnpart[1][2];
        const float mu = S1 * (1.0f / 128.0f);
        const float var = S2 * (1.0f / 128.0f) - mu * mu;
        const float rstd = rsqrtf(var + 1e-5f);
        acc += rstd * (SD - mu * cc_lds[0]) + cc_lds[1];
        cnt += 1.0f;
      }
      mprev = m;
    }
    __syncthreads();                         // B6

    // ---- phase G: h: substep3 mv1 ----
    if (isH) {
      const float uu = fast_tanh(mv16(w1h, hcur, q0) + b1j);
      if (ks == 0) ((_Float16*)u16)[j] = (_Float16)uu;
    }
    __syncthreads();                         // B7

    // ---- phase H: h: substep3 mv2 (final ODE h) ----
    if (isH) {
      hreg = fmaf(stepv, mv16(w2h, u16, q0) + b2j, hreg);
      if (ks == 0) ((_Float16*)hcur)[j] = (_Float16)hreg;
    }
    __syncthreads();                         // B8

    // ---- GRU phase (h-engine) ----
    if (isH) {
      const float pr = mv16(whr, hcur, q0) + bias_lds[j];        // FIX: no extra qsum
      const float pz = mv16(whz, hcur, q0) + bias_lds[Hh + j];
      const float pn = mv16(whn, hcur, q0) + bias_lds[2 * Hh + j];
      const float r = fast_sigmoid(gi_f[j] + pr);
      const float z = fast_sigmoid(gi_f[Hh + j] + pz);
      const float n = fast_tanh(gi_f[2 * Hh + j] + r * pn);
      const float hg = (1.0f - z) * n + z * hreg;
      if (act_lds[t]) hreg = hg;
      if (ks == 0) {
        ((_Float16*)h16[pp ^ 1])[j] = (_Float16)hreg;
        hLN[t & 1][j] = hreg;
      }
    }
    __syncthreads();                         // B9
    pp ^= 1;
  }

  // ---- epilogue: LN of t=1023 ----
  if (wv == 8 || wv == 9) {
    const float hv = hLN[1][lidx];
    float s1 = hv, s2 = hv * hv, sd = hv * gw_l;
#pragma unroll
    for (int o = 1; o < 64; o <<= 1) {
      s1 += __shfl_xor(s1, o); s2 += __shfl_xor(s2, o); sd += __shfl_xor(sd, o);
    }
    if (lane == 0) {
      lnpart[wv - 8][0] = s1; lnpart[wv - 8][1] = s2; lnpart[wv - 8][2] = sd;
    }
  }
  __syncthreads();
  if (tid == 512) {
    if (mprev) {
      const float S1 = lnpart[0][0] + lnpart[1][0];
      const float S2 = lnpart[0][1] + lnpart[1][1];
      const float SD = lnpart[0][2] + lnpart[1][2];
      const float mu = S1 * (1.0f / 128.0f);
      const float var = S2 * (1.0f / 128.0f) - mu * mu;
      const float rstd = rsqrtf(var + 1e-5f);
      acc += rstd * (SD - mu * cc_lds[0]) + cc_lds[1];
      cnt += 1.0f;
    }
    out[b] = acc / fmaxf(cnt, 1.0f);         // FLOAT32 output
  }
}

// ---------------- host ----------------
extern "C" void kernel_launch(void* const* d_in, const int* in_sizes, int n_in,
                              void* d_out, int out_size, void* d_ws, size_t ws_size,
                              hipStream_t stream) {
  const float* x    = (const float*)d_in[0];
  const float* dt   = (const float*)d_in[1];
  const int*   mask = (const int*)d_in[2];
  const float* Wx   = (const float*)d_in[3];
  const float* bx   = (const float*)d_in[4];
  const float* W1   = (const float*)d_in[5];
  const float* b1   = (const float*)d_in[6];
  const float* W2   = (const float*)d_in[7];
  const float* b2   = (const float*)d_in[8];
  const float* Wih  = (const float*)d_in[9];
  const float* bih  = (const float*)d_in[10];
  const float* Whh  = (const float*)d_in[11];
  const float* bhh  = (const float*)d_in[12];
  const float* lng  = (const float*)d_in[13];
  const float* lnb  = (const float*)d_in[14];
  const float* Wh   = (const float*)d_in[15];
  const float* bh   = (const float*)d_in[16];
  float* out = (float*)d_out;

  k_fused<<<dim3(Bb), dim3(1024), 0, stream>>>(
      x, dt, mask, Wx, bx, W1, b1, W2, b2, Wih, bih, Whh, bhh,
      lng, lnb, Wh, bh, out);
}

// Round 16
// 4902.262 us; speedup vs baseline: 1.0234x; 1.0234x over previous
//
#include <hip/hip_runtime.h>

#define Bb 256
#define Ll 1024
#define Gg 16        // batch rows per WG; grid = 256/16 = 16

typedef _Float16 f16x8 __attribute__((ext_vector_type(8)));
typedef float f32x4 __attribute__((ext_vector_type(4)));

__device__ __forceinline__ f32x4 MFMA(f16x8 a, f16x8 b, f32x4 c) {
  return __builtin_amdgcn_mfma_f32_16x16x32_f16(a, b, c, 0, 0, 0);
}
__device__ __forceinline__ float fast_tanh(float x) {
  float e = __expf(2.0f * x);
  return 1.0f - 2.0f / (e + 1.0f);
}
__device__ __forceinline__ float fast_sigmoid(float x) {
  return 1.0f / (1.0f + __expf(-x));
}
__device__ __forceinline__ f16x8 ld8(const float* p) {
  f16x8 v;
#pragma unroll
  for (int e = 0; e < 8; ++e) v[e] = (_Float16)p[e];
  return v;
}

// B-fragment from a [16 b][128 k] f16 buffer, granule-XOR-swizzled.
// lane: b = lane&15, lg = lane>>4; logical k = kt*32 + lg*8 + e.
__device__ __forceinline__ f16x8 bfrag(const _Float16* buf, int b, int lg, int kt) {
  return *(const f16x8*)&buf[(b << 7) + ((((kt << 2) + lg) ^ b) << 3)];
}

// One WG per 16 batch rows. 512 threads, 8 waves; wave w owns output rows
// j = 16w .. 16w+15. A-frag row (lane&15), D: col=lane&15 (=batch), row=lg*4+r.
__global__ __launch_bounds__(512, 1) void k_fused(
    const float* __restrict__ x, const float* __restrict__ dtp,
    const int* __restrict__ mask,
    const float* __restrict__ Wx, const float* __restrict__ bx,
    const float* __restrict__ W1, const float* __restrict__ b1,
    const float* __restrict__ W2, const float* __restrict__ b2,
    const float* __restrict__ Wih, const float* __restrict__ bih,
    const float* __restrict__ Whh, const float* __restrict__ bhh,
    const float* __restrict__ lng, const float* __restrict__ lnb,
    const float* __restrict__ Whd, const float* __restrict__ bhp,
    float* __restrict__ out)
{
  const int b0 = blockIdx.x * Gg;
  const int tid = threadIdx.x;
  const int lane = tid & 63;
  const int w = tid >> 6;             // 0..7
  const int b = lane & 15;            // batch col / A-row-within-tile
  const int lg = lane >> 4;           // 0..3 (k-group)
  const int jrow0 = (w << 4) + (lg << 2);   // output j = jrow0 + r
  const int arow = (w << 4) + b;      // A-fragment row

  __shared__ _Float16 wih_s[384 * 128];        // 96 KB, A-swizzled
  __shared__ _Float16 xch_s[2][2][Gg * 64];    // 8 KB
  __shared__ _Float16 hbuf[Gg * 128];          // 4 KB
  __shared__ _Float16 ubuf[Gg * 128];          // 4 KB
  __shared__ _Float16 xebuf[Gg * 128];         // 4 KB
  __shared__ float gi_s[3 * Gg * 129];         // 24.2 KB (pitch 129: conflict-free)
  __shared__ float dtm_s[2][2][Gg];
  __shared__ int   mfl_s[2][2][Gg];
  __shared__ float lnp[8][3][Gg];
  __shared__ unsigned actb[32];
  __shared__ float cb[1280];                   // b1|b2|bx|bih|bhh|gw
  __shared__ float cc[2];

  if (tid < 32) actb[tid] = 0u;
  __syncthreads();
  // ---- act prepass: global any-mask per t (coalesced over lanes) ----
  for (int t0 = tid; t0 < Ll; t0 += 512) {
    int a = 0;
#pragma unroll 8
    for (int bb = 0; bb < Bb; ++bb) a |= mask[(size_t)bb * Ll + t0];
    if (a) atomicOr(&actb[t0 >> 5], 1u << (t0 & 31));
  }
  // ---- Wih -> LDS f16 in A-fragment granule swizzle ----
  for (int idx = tid; idx < 384 * 128; idx += 512) {
    const int r = idx >> 7, k = idx & 127;
    wih_s[(r << 7) + ((((k >> 3) ^ (r & 15))) << 3) + (k & 7)] = (_Float16)Wih[idx];
  }
  // ---- bias/constants ----
  for (int i = tid; i < 128; i += 512) {
    cb[i] = b1[i]; cb[128 + i] = b2[i]; cb[256 + i] = bx[i];
    cb[1152 + i] = lng[i] * Whd[i];
  }
  for (int i = tid; i < 384; i += 512) { cb[384 + i] = bih[i]; cb[768 + i] = bhh[i]; }
  if (tid == 0) {
    float s1 = 0.f, s0 = 0.f;
    for (int i = 0; i < 128; ++i) { s1 += lng[i] * Whd[i]; s0 += lnb[i] * Whd[i]; }
    cc[0] = s1; cc[1] = s0 + bhp[0];
  }
  for (int i = tid; i < Gg * 128; i += 512) hbuf[i] = (_Float16)0.f;

  // ---- register-stationary A-fragments (88 u32) ----
  f16x8 w1f[4], w2f[4], whrf[4], whzf[4], whnf[4], wxf2[2];
  const int koff = lg << 3;
#pragma unroll
  for (int kt = 0; kt < 4; ++kt) {
    const int kb = kt * 32 + koff;
    w1f[kt]  = ld8(W1  + (size_t)arow * 128 + kb);
    w2f[kt]  = ld8(W2  + (size_t)arow * 128 + kb);
    whrf[kt] = ld8(Whh + (size_t)arow * 128 + kb);
    whzf[kt] = ld8(Whh + (size_t)(128 + arow) * 128 + kb);
    whnf[kt] = ld8(Whh + (size_t)(256 + arow) * 128 + kb);
  }
#pragma unroll
  for (int kt = 0; kt < 2; ++kt)
    wxf2[kt] = ld8(Wx + (size_t)arow * 64 + kt * 32 + koff);

  // ---- initial x/dt/mask chunk (steps 0,1 -> buf 0) ----
  if (tid >= 256) {
    const int u = tid - 256, ts = u >> 7, bb = (u >> 3) & 15, gr = u & 7;
    const float* sp = x + ((size_t)(b0 + bb) * Ll + ts) * 64 + gr * 8;
    f16x8 v = ld8(sp);
    *(f16x8*)&xch_s[0][ts & 1][bb * 64 + ((gr ^ (bb & 7)) << 3)] = v;
  } else if (tid >= 224) {
    const int v = tid - 224, slq = v >> 4, bb = v & 15;
    const float dv = dtp[(size_t)(b0 + bb) * Ll + slq];
    const int mv = mask[(size_t)(b0 + bb) * Ll + slq];
    dtm_s[0][slq][bb] = dv * (float)mv * 0.25f;
    mfl_s[0][slq][bb] = mv;
  }

  float hreg[4] = {0.f, 0.f, 0.f, 0.f};
  float accb = 0.f, cntb = 0.f;       // wave 0 lanes 0..15
  __syncthreads();

#pragma unroll 1
  for (int t = 0; t < Ll; ++t) {
    const int buf = (t >> 1) & 1, sl = t & 1;
    const float sv = dtm_s[buf][sl][b];

    // ---- P0: xe = relu(Wx . x_t + bx) ----
    {
      f32x4 acc = {0.f, 0.f, 0.f, 0.f};
      const _Float16* xr = xch_s[buf][sl];
#pragma unroll
      for (int kt = 0; kt < 2; ++kt) {
        const f16x8 bx8 = *(const f16x8*)&xr[(b << 6) + ((((kt << 2) + lg) ^ (b & 7)) << 3)];
        acc = MFMA(wxf2[kt], bx8, acc);
      }
#pragma unroll
      for (int r = 0; r < 4; ++r) {
        const int j = jrow0 + r;
        const float v = fmaxf(acc[r] + cb[256 + j], 0.f);
        xebuf[(b << 7) + (((j >> 3) ^ b) << 3) + (j & 7)] = (_Float16)v;
      }
    }
    __syncthreads();

    // ---- P1..P8: 4 Euler substeps (u then h), gi fused into P1..P3 ----
#pragma unroll
    for (int s = 0; s < 4; ++s) {
      { // u = tanh(W1 . h)
        f32x4 acc = {0.f, 0.f, 0.f, 0.f};
#pragma unroll
        for (int kt = 0; kt < 4; ++kt) acc = MFMA(w1f[kt], bfrag(hbuf, b, lg, kt), acc);
        if (s == 0) { // gi_r
          f32x4 ga = {0.f, 0.f, 0.f, 0.f};
#pragma unroll
          for (int kt = 0; kt < 4; ++kt) {
            const int row = (w << 4) + b;   // gate 0 rows
            const f16x8 a8 = *(const f16x8*)&wih_s[(row << 7) + ((((kt << 2) + lg) ^ b) << 3)];
            ga = MFMA(a8, bfrag(xebuf, b, lg, kt), ga);
          }
#pragma unroll
          for (int r = 0; r < 4; ++r) {
            const int j = jrow0 + r;
            gi_s[(b) * 129 + j] = ga[r] + cb[384 + j];
          }
        }
#pragma unroll
        for (int r = 0; r < 4; ++r) {
          const int j = jrow0 + r;
          const float uu = fast_tanh(acc[r] + cb[j]);
          ubuf[(b << 7) + (((j >> 3) ^ b) << 3) + (j & 7)] = (_Float16)uu;
        }
      }
      __syncthreads();
      { // h += sv * (W2 . u + b2)
        f32x4 acc = {0.f, 0.f, 0.f, 0.f};
#pragma unroll
        for (int kt = 0; kt < 4; ++kt) acc = MFMA(w2f[kt], bfrag(ubuf, b, lg, kt), acc);
        if (s == 0) { // gi_z
          f32x4 ga = {0.f, 0.f, 0.f, 0.f};
#pragma unroll
          for (int kt = 0; kt < 4; ++kt) {
            const int row = 128 + (w << 4) + b;
            const f16x8 a8 = *(const f16x8*)&wih_s[(row << 7) + ((((kt << 2) + lg) ^ b) << 3)];
            ga = MFMA(a8, bfrag(xebuf, b, lg, kt), ga);
          }
#pragma unroll
          for (int r = 0; r < 4; ++r) {
            const int j = jrow0 + r;
            gi_s[(16 + b) * 129 + j] = ga[r] + cb[384 + 128 + j];
          }
        } else if (s == 1) { // gi_n
          f32x4 ga = {0.f, 0.f, 0.f, 0.f};
#pragma unroll
          for (int kt = 0; kt < 4; ++kt) {
            const int row = 256 + (w << 4) + b;
            const f16x8 a8 = *(const f16x8*)&wih_s[(row << 7) + ((((kt << 2) + lg) ^ b) << 3)];
            ga = MFMA(a8, bfrag(xebuf, b, lg, kt), ga);
          }
#pragma unroll
          for (int r = 0; r < 4; ++r) {
            const int j = jrow0 + r;
            gi_s[(32 + b) * 129 + j] = ga[r] + cb[384 + 256 + j];
          }
        }
#pragma unroll
        for (int r = 0; r < 4; ++r) {
          const int j = jrow0 + r;
          hreg[r] = fmaf(sv, acc[r] + cb[128 + j], hreg[r]);
          hbuf[(b << 7) + (((j >> 3) ^ b) << 3) + (j & 7)] = (_Float16)hreg[r];
        }
      }
      __syncthreads();
    }

    // ---- P9a: GRU matvecs (share B-frags across 3 gates) ----
    f32x4 ar = {0.f, 0.f, 0.f, 0.f}, az = ar, an = ar;
#pragma unroll
    for (int kt = 0; kt < 4; ++kt) {
      const f16x8 hv = bfrag(hbuf, b, lg, kt);
      ar = MFMA(whrf[kt], hv, ar);
      az = MFMA(whzf[kt], hv, az);
      an = MFMA(whnf[kt], hv, an);
    }
    __syncthreads();

    // ---- P9b: gates + h_new + LN partials ----
    {
      const int actv = (actb[t >> 5] >> (t & 31)) & 1;
      float s1 = 0.f, s2 = 0.f, sd = 0.f;
#pragma unroll
      for (int r = 0; r < 4; ++r) {
        const int j = jrow0 + r;
        const float rr = fast_sigmoid(gi_s[b * 129 + j] + ar[r] + cb[768 + j]);
        const float zz = fast_sigmoid(gi_s[(16 + b) * 129 + j] + az[r] + cb[768 + 128 + j]);
        const float nn = fast_tanh(gi_s[(32 + b) * 129 + j] + rr * (an[r] + cb[768 + 256 + j]));
        const float hg = (1.f - zz) * nn + zz * hreg[r];
        if (actv) hreg[r] = hg;
        hbuf[(b << 7) + (((j >> 3) ^ b) << 3) + (j & 7)] = (_Float16)hreg[r];
        s1 += hreg[r]; s2 += hreg[r] * hreg[r]; sd += hreg[r] * cb[1152 + j];
      }
      s1 += __shfl_xor(s1, 16); s2 += __shfl_xor(s2, 16); sd += __shfl_xor(sd, 16);
      s1 += __shfl_xor(s1, 32); s2 += __shfl_xor(s2, 32); sd += __shfl_xor(sd, 32);
      if (lane < 16) { lnp[w][0][b] = s1; lnp[w][1][b] = s2; lnp[w][2][b] = sd; }
    }
    __syncthreads();

    // ---- P10: logit accumulate (wave 0) || chunk refill (threads >= 224) ----
    if (w == 0) {
      if (lane < 16) {
        float S1 = 0.f, S2 = 0.f, SD = 0.f;
#pragma unroll
        for (int q = 0; q < 8; ++q) {
          S1 += lnp[q][0][lane]; S2 += lnp[q][1][lane]; SD += lnp[q][2][lane];
        }
        if (mfl_s[buf][sl][lane]) {
          const float mu = S1 * (1.0f / 128.0f);
          const float var = S2 * (1.0f / 128.0f) - mu * mu;
          const float rstd = rsqrtf(var + 1e-5f);
          accb += rstd * (SD - mu * cc[0]) + cc[1];
          cntb += 1.f;
        }
      }
    } else if ((t & 1) == 1 && t + 1 < Ll) {
      const int nbuf = ((t >> 1) + 1) & 1;
      if (tid >= 256) {
        const int u = tid - 256, ts = u >> 7, bb = (u >> 3) & 15, gr = u & 7;
        const int st = t + 1 + ts;
        if (st < Ll) {
          f16x8 v = ld8(x + ((size_t)(b0 + bb) * Ll + st) * 64 + gr * 8);
          *(f16x8*)&xch_s[nbuf][st & 1][bb * 64 + ((gr ^ (bb & 7)) << 3)] = v;
        }
      } else if (tid >= 224) {
        const int v2 = tid - 224, slq = v2 >> 4, bb = v2 & 15;
        const int st = t + 1 + slq;
        if (st < Ll) {
          const float dv = dtp[(size_t)(b0 + bb) * Ll + st];
          const int mv = mask[(size_t)(b0 + bb) * Ll + st];
          dtm_s[nbuf][st & 1][bb] = dv * (float)mv * 0.25f;
          mfl_s[nbuf][st & 1][bb] = mv;
        }
      }
    }
    __syncthreads();
  }

  if (w == 0 && lane < 16) out[b0 + lane] = accb / fmaxf(cntb, 1.f);
}

// ---------------- host ----------------
extern "C" void kernel_launch(void* const* d_in, const int* in_sizes, int n_in,
                              void* d_out, int out_size, void* d_ws, size_t ws_size,
                              hipStream_t stream) {
  const float* x    = (const float*)d_in[0];
  const float* dt   = (const float*)d_in[1];
  const int*   mask = (const int*)d_in[2];
  const float* Wx   = (const float*)d_in[3];
  const float* bx   = (const float*)d_in[4];
  const float* W1   = (const float*)d_in[5];
  const float* b1   = (const float*)d_in[6];
  const float* W2   = (const float*)d_in[7];
  const float* b2   = (const float*)d_in[8];
  const float* Wih  = (const float*)d_in[9];
  const float* bih  = (const float*)d_in[10];
  const float* Whh  = (const float*)d_in[11];
  const float* bhh  = (const float*)d_in[12];
  const float* lng  = (const float*)d_in[13];
  const float* lnb  = (const float*)d_in[14];
  const float* Wh   = (const float*)d_in[15];
  const float* bh   = (const float*)d_in[16];
  float* out = (float*)d_out;

  k_fused<<<dim3(Bb / Gg), dim3(512), 0, stream>>>(
      x, dt, mask, Wx, bx, W1, b1, W2, b2, Wih, bih, Whh, bhh,
      lng, lnb, Wh, bh, out);
}

// Round 17
// 4297.301 us; speedup vs baseline: 1.1674x; 1.1408x over previous
//
#include <hip/hip_runtime.h>

#define Bb 256
#define Ll 1024
#define Gg 16        // batch rows per WG; grid = 16
#define CH 4         // x/dt/mask chunk steps (double-buffered)

typedef _Float16 f16x8 __attribute__((ext_vector_type(8)));
typedef _Float16 f16x4 __attribute__((ext_vector_type(4)));
typedef float f32x4 __attribute__((ext_vector_type(4)));

__device__ __forceinline__ f32x4 MFMA(f16x8 a, f16x8 b, f32x4 c) {
  return __builtin_amdgcn_mfma_f32_16x16x32_f16(a, b, c, 0, 0, 0);
}
__device__ __forceinline__ float fast_tanh(float x) {
  float e = __expf(2.0f * x);
  return 1.0f - 2.0f / (e + 1.0f);
}
__device__ __forceinline__ float fast_sigmoid(float x) {
  return 1.0f / (1.0f + __expf(-x));
}
__device__ __forceinline__ f16x8 ld8(const float* __restrict__ p) {
  const float4 a = *(const float4*)p;
  const float4 c = *(const float4*)(p + 4);
  f16x8 v;
  v[0]=(_Float16)a.x; v[1]=(_Float16)a.y; v[2]=(_Float16)a.z; v[3]=(_Float16)a.w;
  v[4]=(_Float16)c.x; v[5]=(_Float16)c.y; v[6]=(_Float16)c.z; v[7]=(_Float16)c.w;
  return v;
}
// B-fragment from [16 b][128 k] f16 state buffer, granule-XOR swizzle (r16-verified)
__device__ __forceinline__ f16x8 bfrag(const _Float16* __restrict__ buf, int b, int lg, int kt) {
  return *(const f16x8*)&buf[(b << 7) + ((((kt << 2) + lg) ^ b) << 3)];
}
// store this lane's 4 D-values (j = jrow0..+3, one granule) as f16, single b64
__device__ __forceinline__ void st4(_Float16* __restrict__ buf, int b, int g, int sub, f32x4 v) {
  f16x4 h;
  h[0]=(_Float16)v[0]; h[1]=(_Float16)v[1]; h[2]=(_Float16)v[2]; h[3]=(_Float16)v[3];
  *(f16x4*)&buf[(b << 7) + ((g ^ b) << 3) + (sub << 2)] = h;
}

__global__ __launch_bounds__(512, 1) void k_fused(
    const float* __restrict__ x, const float* __restrict__ dtp,
    const int* __restrict__ mask,
    const float* __restrict__ Wx, const float* __restrict__ bx,
    const float* __restrict__ W1, const float* __restrict__ b1,
    const float* __restrict__ W2, const float* __restrict__ b2,
    const float* __restrict__ Wih, const float* __restrict__ bih,
    const float* __restrict__ Whh, const float* __restrict__ bhh,
    const float* __restrict__ lng, const float* __restrict__ lnb,
    const float* __restrict__ Whd, const float* __restrict__ bhp,
    float* __restrict__ out)
{
  const int b0 = blockIdx.x * Gg;
  const int tid = threadIdx.x;
  const int lane = tid & 63;
  const int w = tid >> 6;                   // 0..7
  const int b = lane & 15;                  // batch col
  const int lg = lane >> 4;                 // 0..3
  const int jrow0 = (w << 4) + (lg << 2);   // j = jrow0 + r
  const int g = (w << 1) + (lg >> 1);       // j granule (j>>3)
  const int sub = lg & 1;
  const int arow = (w << 4) + b;            // A-fragment row

  __shared__ _Float16 wih_s[384 * 128];          // 96 KB, A-swizzled
  __shared__ _Float16 xch[2][CH][Gg * 64];       // 16 KB
  __shared__ _Float16 hbuf[2][Gg * 128];         // 8 KB (step-parity dbuf)
  __shared__ _Float16 ubuf[Gg * 128];            // 4 KB
  __shared__ _Float16 xebuf[2][Gg * 128];        // 8 KB (step-parity dbuf)
  __shared__ float dtm_s[2][CH][Gg];
  __shared__ int   mfl_s[2][CH][Gg];
  __shared__ float lnp[8][3][Gg];
  __shared__ unsigned actb[32];
  __shared__ float cb[1280];                     // b1|b2|bx|bih(384)|bhh(384)|gw
  __shared__ float cc[2];

  if (tid < 32) actb[tid] = 0u;
  __syncthreads();
  // ---- act prepass ----
  for (int t0 = tid; t0 < Ll; t0 += 512) {
    int a = 0;
#pragma unroll 8
    for (int bb = 0; bb < Bb; ++bb) a |= mask[(size_t)bb * Ll + t0];
    if (a) atomicOr(&actb[t0 >> 5], 1u << (t0 & 31));
  }
  // ---- Wih -> LDS (A-fragment granule swizzle, r16-verified) ----
  for (int idx = tid; idx < 384 * 128; idx += 512) {
    const int r = idx >> 7, k = idx & 127;
    wih_s[(r << 7) + (((k >> 3) ^ (r & 15)) << 3) + (k & 7)] = (_Float16)Wih[idx];
  }
  // ---- constants ----
  for (int i = tid; i < 128; i += 512) {
    cb[i] = b1[i]; cb[128 + i] = b2[i]; cb[256 + i] = bx[i];
    cb[1152 + i] = lng[i] * Whd[i];
  }
  for (int i = tid; i < 384; i += 512) { cb[384 + i] = bih[i]; cb[768 + i] = bhh[i]; }
  if (tid == 0) {
    float s1 = 0.f, s0 = 0.f;
    for (int i = 0; i < 128; ++i) { s1 += lng[i] * Whd[i]; s0 += lnb[i] * Whd[i]; }
    cc[0] = s1; cc[1] = s0 + bhp[0];
  }
  for (int i = tid; i < Gg * 128; i += 512) {
    hbuf[0][i] = (_Float16)0.f; hbuf[1][i] = (_Float16)0.f;
  }
  // ---- chunk 0 (steps 0..3) ----
  {
    const int ts = tid >> 7, bb = (tid >> 3) & 15, gr = tid & 7;
    const f16x8 v = ld8(x + ((size_t)(b0 + bb) * Ll + ts) * 64 + gr * 8);
    *(f16x8*)&xch[0][ts][(bb << 6) + ((gr ^ (bb & 7)) << 3)] = v;
    if (tid < CH * Gg) {
      const int ts2 = tid >> 4, bb2 = tid & 15;
      const float dv = dtp[(size_t)(b0 + bb2) * Ll + ts2];
      const int mv = mask[(size_t)(b0 + bb2) * Ll + ts2];
      dtm_s[0][ts2][bb2] = dv * (float)mv * 0.25f;
      mfl_s[0][ts2][bb2] = mv;
    }
  }
  // ---- register-stationary A-fragments (88 u32) ----
  f16x8 w1f[4], w2f[4], whrf[4], whzf[4], whnf[4], wxf2[2];
#pragma unroll
  for (int kt = 0; kt < 4; ++kt) {
    const int kb = kt * 32 + (lg << 3);
    w1f[kt]  = ld8(W1  + (size_t)arow * 128 + kb);
    w2f[kt]  = ld8(W2  + (size_t)arow * 128 + kb);
    whrf[kt] = ld8(Whh + (size_t)arow * 128 + kb);
    whzf[kt] = ld8(Whh + (size_t)(128 + arow) * 128 + kb);
    whnf[kt] = ld8(Whh + (size_t)(256 + arow) * 128 + kb);
  }
#pragma unroll
  for (int kt = 0; kt < 2; ++kt)
    wxf2[kt] = ld8(Wx + (size_t)arow * 64 + kt * 32 + (lg << 3));

  float hreg[4] = {0.f, 0.f, 0.f, 0.f};
  float accb = 0.f, cntb = 0.f;
  int mreg = 0;
  __syncthreads();

  // ---- prologue: xe_0 ----
  {
    f32x4 acc = {0.f, 0.f, 0.f, 0.f};
#pragma unroll
    for (int kt = 0; kt < 2; ++kt) {
      const f16x8 xv = *(const f16x8*)&xch[0][0][(b << 6) + ((((kt << 2) + lg) ^ (b & 7)) << 3)];
      acc = MFMA(wxf2[kt], xv, acc);
    }
    f32x4 xx;
#pragma unroll
    for (int r = 0; r < 4; ++r) xx[r] = fmaxf(acc[r] + cb[256 + jrow0 + r], 0.f);
    st4(xebuf[0], b, g, sub, xx);
  }
  __syncthreads();

#pragma unroll 1
  for (int t = 0; t < Ll; ++t) {
    const int cbuf = (t >> 2) & 1, tc = t & 3;
    _Float16* hb = hbuf[t & 1];
    const float sv = dtm_s[cbuf][tc][b];

    // ================= P1: mv1 s0 | logit(t-1) | refill =================
    {
      f32x4 acc = {0.f, 0.f, 0.f, 0.f};
#pragma unroll
      for (int kt = 0; kt < 4; ++kt) acc = MFMA(w1f[kt], bfrag(hb, b, lg, kt), acc);
      f32x4 uu;
#pragma unroll
      for (int r = 0; r < 4; ++r) uu[r] = fast_tanh(acc[r] + cb[jrow0 + r]);
      st4(ubuf, b, g, sub, uu);

      if (w == 0 && lane < 16 && t > 0) {
        float S1 = 0.f, S2 = 0.f, SD = 0.f;
#pragma unroll
        for (int q = 0; q < 8; ++q) {
          S1 += lnp[q][0][lane]; S2 += lnp[q][1][lane]; SD += lnp[q][2][lane];
        }
        if (mreg) {
          const float mu = S1 * (1.0f / 128.0f);
          const float var = S2 * (1.0f / 128.0f) - mu * mu;
          const float rstd = rsqrtf(var + 1e-5f);
          accb += rstd * (SD - mu * cc[0]) + cc[1];
          cntb += 1.f;
        }
      }
      if (tc == 0) {
        const int cnext = (t >> 2) + 1;
        if (cnext * CH < Ll) {
          const int nb = cnext & 1;
          const int ts = tid >> 7, bb = (tid >> 3) & 15, gr = tid & 7;
          const int st = cnext * CH + ts;
          const f16x8 v = ld8(x + ((size_t)(b0 + bb) * Ll + st) * 64 + gr * 8);
          *(f16x8*)&xch[nb][ts][(bb << 6) + ((gr ^ (bb & 7)) << 3)] = v;
          if (tid < CH * Gg) {
            const int ts2 = tid >> 4, bb2 = tid & 15;
            const int st2 = cnext * CH + ts2;
            const float dv = dtp[(size_t)(b0 + bb2) * Ll + st2];
            const int mv = mask[(size_t)(b0 + bb2) * Ll + st2];
            dtm_s[nb][ts2][bb2] = dv * (float)mv * 0.25f;
            mfl_s[nb][ts2][bb2] = mv;
          }
        }
      }
    }
    __syncthreads();

    // ============ P2..P8: rest of the 4 Euler substeps ============
#pragma unroll
    for (int s = 0; s < 4; ++s) {
      { // mv2: h += sv*(W2.u + b2)
        f32x4 acc = {0.f, 0.f, 0.f, 0.f};
#pragma unroll
        for (int kt = 0; kt < 4; ++kt) acc = MFMA(w2f[kt], bfrag(ubuf, b, lg, kt), acc);
        f32x4 hh;
#pragma unroll
        for (int r = 0; r < 4; ++r) {
          hreg[r] = fmaf(sv, acc[r] + cb[128 + jrow0 + r], hreg[r]);
          hh[r] = hreg[r];
        }
        st4(hb, b, g, sub, hh);
      }
      __syncthreads();
      if (s < 3) { // mv1 of next substep
        f32x4 acc = {0.f, 0.f, 0.f, 0.f};
#pragma unroll
        for (int kt = 0; kt < 4; ++kt) acc = MFMA(w1f[kt], bfrag(hb, b, lg, kt), acc);
        f32x4 uu;
#pragma unroll
        for (int r = 0; r < 4; ++r) uu[r] = fast_tanh(acc[r] + cb[jrow0 + r]);
        st4(ubuf, b, g, sub, uu);
        __syncthreads();
      }
    }

    // ================= P9: gi + GRU + xe_{t+1} + LN =================
    {
      const _Float16* xeb = xebuf[t & 1];
      // r gate
      f32x4 ga = {0.f, 0.f, 0.f, 0.f}, am = {0.f, 0.f, 0.f, 0.f};
#pragma unroll
      for (int kt = 0; kt < 4; ++kt) {
        const f16x8 a8 = *(const f16x8*)&wih_s[((size_t)arow << 7) + ((((kt << 2) + lg) ^ b) << 3)];
        ga = MFMA(a8, bfrag(xeb, b, lg, kt), ga);
        am = MFMA(whrf[kt], bfrag(hb, b, lg, kt), am);
      }
      float rr[4];
#pragma unroll
      for (int r = 0; r < 4; ++r)
        rr[r] = fast_sigmoid(ga[r] + cb[384 + jrow0 + r] + am[r] + cb[768 + jrow0 + r]);
      // z gate
      f32x4 gz = {0.f, 0.f, 0.f, 0.f}, az = {0.f, 0.f, 0.f, 0.f};
#pragma unroll
      for (int kt = 0; kt < 4; ++kt) {
        const f16x8 a8 = *(const f16x8*)&wih_s[((size_t)(128 + arow) << 7) + ((((kt << 2) + lg) ^ b) << 3)];
        gz = MFMA(a8, bfrag(xeb, b, lg, kt), gz);
        az = MFMA(whzf[kt], bfrag(hb, b, lg, kt), az);
      }
      float zz[4];
#pragma unroll
      for (int r = 0; r < 4; ++r)
        zz[r] = fast_sigmoid(gz[r] + cb[384 + 128 + jrow0 + r] + az[r] + cb[768 + 128 + jrow0 + r]);
      // n gate
      f32x4 gn = {0.f, 0.f, 0.f, 0.f}, an = {0.f, 0.f, 0.f, 0.f};
#pragma unroll
      for (int kt = 0; kt < 4; ++kt) {
        const f16x8 a8 = *(const f16x8*)&wih_s[((size_t)(256 + arow) << 7) + ((((kt << 2) + lg) ^ b) << 3)];
        gn = MFMA(a8, bfrag(xeb, b, lg, kt), gn);
        an = MFMA(whnf[kt], bfrag(hb, b, lg, kt), an);
      }
      const int actv = (actb[t >> 5] >> (t & 31)) & 1;
      f32x4 hn;
      float s1 = 0.f, s2 = 0.f, sd = 0.f;
#pragma unroll
      for (int r = 0; r < 4; ++r) {
        const int j = jrow0 + r;
        const float nn = fast_tanh(gn[r] + cb[384 + 256 + j] + rr[r] * (an[r] + cb[768 + 256 + j]));
        const float hg = (1.f - zz[r]) * nn + zz[r] * hreg[r];
        if (actv) hreg[r] = hg;
        hn[r] = hreg[r];
        s1 += hreg[r]; s2 += hreg[r] * hreg[r]; sd += hreg[r] * cb[1152 + j];
      }
      st4(hbuf[(t + 1) & 1], b, g, sub, hn);
      // xe_{t+1}
      if (t + 1 < Ll) {
        const int nslot = (t + 1) & 3, ncb = ((t + 1) >> 2) & 1;
        f32x4 acc = {0.f, 0.f, 0.f, 0.f};
#pragma unroll
        for (int kt = 0; kt < 2; ++kt) {
          const f16x8 xv = *(const f16x8*)&xch[ncb][nslot][(b << 6) + ((((kt << 2) + lg) ^ (b & 7)) << 3)];
          acc = MFMA(wxf2[kt], xv, acc);
        }
        f32x4 xx;
#pragma unroll
        for (int r = 0; r < 4; ++r) xx[r] = fmaxf(acc[r] + cb[256 + jrow0 + r], 0.f);
        st4(xebuf[(t + 1) & 1], b, g, sub, xx);
      }
      // LN partials
      s1 += __shfl_xor(s1, 16); s2 += __shfl_xor(s2, 16); sd += __shfl_xor(sd, 16);
      s1 += __shfl_xor(s1, 32); s2 += __shfl_xor(s2, 32); sd += __shfl_xor(sd, 32);
      if (lane < 16) { lnp[w][0][b] = s1; lnp[w][1][b] = s2; lnp[w][2][b] = sd; }
      if (w == 0 && lane < 16) mreg = mfl_s[cbuf][tc][lane];
    }
    __syncthreads();
  }

  // ---- epilogue: logit for t=1023 ----
  if (w == 0 && lane < 16) {
    float S1 = 0.f, S2 = 0.f, SD = 0.f;
#pragma unroll
    for (int q = 0; q < 8; ++q) {
      S1 += lnp[q][0][lane]; S2 += lnp[q][1][lane]; SD += lnp[q][2][lane];
    }
    if (mreg) {
      const float mu = S1 * (1.0f / 128.0f);
      const float var = S2 * (1.0f / 128.0f) - mu * mu;
      const float rstd = rsqrtf(var + 1e-5f);
      accb += rstd * (SD - mu * cc[0]) + cc[1];
      cntb += 1.f;
    }
    out[b0 + lane] = accb / fmaxf(cntb, 1.f);
  }
}

// ---------------- host ----------------
extern "C" void kernel_launch(void* const* d_in, const int* in_sizes, int n_in,
                              void* d_out, int out_size, void* d_ws, size_t ws_size,
                              hipStream_t stream) {
  const float* x    = (const float*)d_in[0];
  const float* dt   = (const float*)d_in[1];
  const int*   mask = (const int*)d_in[2];
  const float* Wx   = (const float*)d_in[3];
  const float* bx   = (const float*)d_in[4];
  const float* W1   = (const float*)d_in[5];
  const float* b1   = (const float*)d_in[6];
  const float* W2   = (const float*)d_in[7];
  const float* b2   = (const float*)d_in[8];
  const float* Wih  = (const float*)d_in[9];
  const float* bih  = (const float*)d_in[10];
  const float* Whh  = (const float*)d_in[11];
  const float* bhh  = (const float*)d_in[12];
  const float* lng  = (const float*)d_in[13];
  const float* lnb  = (const float*)d_in[14];
  const float* Wh   = (const float*)d_in[15];
  const float* bh   = (const float*)d_in[16];
  float* out = (float*)d_out;

  k_fused<<<dim3(Bb / Gg), dim3(512), 0, stream>>>(
      x, dt, mask, Wx, bx, W1, b1, W2, b2, Wih, bih, Whh, bhh,
      lng, lnb, Wh, bh, out);
}